// Round 1
// 450.777 us; speedup vs baseline: 1.0190x; 1.0190x over previous
//
#include <hip/hip_runtime.h>

// Problem constants
#define N_PTS   100000
#define P_CELLS 409600          // 640*640
#define NCLOUD  4               // B=2 batches x {prev, cur}; cloud c = b*2 + t

// Workspace layout (~13 MB used):
//   [0)      k0[64],k1[64],k2[64],k3[64]  fused constants (1 KB)
//   [1024)   head[4*P] ints               (6.55 MB)
//   [+...]   node[4*N] float4             (6.4 MB)  {x,y,z,next-as-bits}
#define WS_HEAD_OFF 1024

typedef float v2f __attribute__((ext_vector_type(2)));
typedef float v4f __attribute__((ext_vector_type(4)));

// ---------------------------------------------------------------------------
// Kernel 1: build per-cell linked lists of masked points with fat nodes.
//   head[c*P + p] -> most recent gid, node[gid].w -> prev gid bits, -1 ends.
// Block 0 additionally fuses the Linear+BN constants (was its own kernel;
// consts are only read by gather, which is a later dispatch -> no race).
// ---------------------------------------------------------------------------
__global__ void build_lists(
    const float* __restrict__ prev_pcl, const int* __restrict__ prev_mask,
    const int*   __restrict__ prev_grid,
    const float* __restrict__ cur_pcl,  const int* __restrict__ cur_mask,
    const int*   __restrict__ cur_grid,
    const float* __restrict__ W,     const float* __restrict__ bvec,
    const float* __restrict__ gamma, const float* __restrict__ beta,
    const float* __restrict__ mean,  const float* __restrict__ var,
    float* __restrict__ k,
    int* __restrict__ head, float4* __restrict__ node)
{
    if (blockIdx.x == 0 && threadIdx.x < 64) {
        const int d = threadIdx.x;
        const float s = gamma[d] * rsqrtf(var[d] + 1e-5f);
        k[d]       = W[d * 3 + 0] * s;
        k[64 + d]  = W[d * 3 + 1] * s;
        k[128 + d] = W[d * 3 + 2] * s;
        k[192 + d] = (bvec[d] - mean[d]) * s + beta[d];
    }

    int gid = blockIdx.x * blockDim.x + threadIdx.x;
    if (gid >= NCLOUD * N_PTS) return;
    int c = gid / N_PTS;
    int n = gid - c * N_PTS;
    int t = c & 1;
    int b = c >> 1;
    const int*   msk = t ? cur_mask : prev_mask;
    const int*   grd = t ? cur_grid : prev_grid;
    const float* pcl = t ? cur_pcl  : prev_pcl;
    int e = b * N_PTS + n;
    if (!msk[e]) return;
    int p = grd[e];
    const float* q = pcl + (size_t)e * 3;
    int old = atomicExch(&head[c * P_CELLS + p], gid);
    node[gid] = make_float4(q[0], q[1], q[2], __int_as_float(old));
}

// ---------------------------------------------------------------------------
// Kernel 2: gather. One thread per (cloud c, cell p): chase chain (one 16 B
// load per hop), accumulate acc in VGPRs. Inner loop is PACKED FP32
// (ext_vector_type(2) -> v_pk_fma_f32 / v_pk_max_f32) to halve VALU issue:
// 32 iterations x {3 pk_fma + pk_max + pk_fma} instead of 64 scalar.
// All acc indices are compile-time constants (full unroll) — runtime
// indexing demoted acc to scratch in a prior session and cost +160 us.
// Epilogue: LDS transpose per 16-feature group; wave stores are 16 B/lane
// NONTEMPORAL (output is write-once streaming, 419 MB >> L2 — nt keeps L2
// free for the node chain lines). head is read-once -> nt load too.
// ---------------------------------------------------------------------------
#define LDS_STRIDE 260   // 260 words = 1040 B = 65*16 -> rows stay 16B-aligned
__global__ __launch_bounds__(256) void gather_kernel(
    const int* __restrict__ head, const float4* __restrict__ node,
    const float* __restrict__ k,   // k0|k1|k2|k3, 64 each
    float* __restrict__ out)
{
    __shared__ float lds[16 * LDS_STRIDE];

    const int tid  = threadIdx.x;
    const int lane = tid & 63;
    const int wv   = tid >> 6;                          // wave id 0..3
    const int c    = blockIdx.y;                        // cloud 0..3
    const int cell0 = blockIdx.x * 256;                 // block's first cell
    const int p    = cell0 + tid;

    int idx = __builtin_nontemporal_load(&head[c * P_CELLS + p]);  // coalesced

    v2f acc[32];
#pragma unroll
    for (int i = 0; i < 32; ++i) acc[i] = (v2f){0.f, 0.f};

    const v2f* __restrict__ k0 = (const v2f*)(k);        // wave-uniform -> s_load
    const v2f* __restrict__ k1 = (const v2f*)(k + 64);
    const v2f* __restrict__ k2 = (const v2f*)(k + 128);
    const v2f* __restrict__ k3 = (const v2f*)(k + 192);

    while (__ballot(idx >= 0)) {
        const bool act = (idx >= 0);
        float4 nd = node[act ? idx : 0];                // predicated fat node
        const float m = act ? 1.f : 0.f;
        if (act) idx = __float_as_int(nd.w);
        v2f xv = nd.x, yv = nd.y, zv = nd.z, mv = m;    // scalar splats
        const v2f zero = (v2f){0.f, 0.f};
#pragma unroll
        for (int i = 0; i < 32; ++i) {
            v2f v = __builtin_elementwise_fma(xv, k0[i],
                    __builtin_elementwise_fma(yv, k1[i],
                    __builtin_elementwise_fma(zv, k2[i], k3[i])));
            v2f r = __builtin_elementwise_max(v, zero); // max kills NaN from poison node[0]
            acc[i] = __builtin_elementwise_fma(r, mv, acc[i]);
        }
    }

    // Epilogue: 4 groups of 16 features through LDS. FULL unroll: all acc[]
    // indices static -> acc stays in VGPRs.
    float* obase = out + (size_t)c * 64u * P_CELLS + cell0;
#pragma unroll
    for (int g = 0; g < 4; ++g) {
        __syncthreads();                                // reads(g-1) done
#pragma unroll
        for (int f = 0; f < 16; ++f) {
            const int feat = g * 16 + f;                // static
            lds[f * LDS_STRIDE + tid] = acc[feat >> 1][feat & 1];
        }
        __syncthreads();
#pragma unroll
        for (int r = 0; r < 4; ++r) {
            const int f = r * 4 + wv;                   // wave-uniform feature
            v4f v = *(const v4f*)&lds[f * LDS_STRIDE + lane * 4];
            __builtin_nontemporal_store(
                v, (v4f*)(obase + (size_t)(g * 16 + f) * P_CELLS + lane * 4));
        }
    }
}

// ---------------------------------------------------------------------------
extern "C" void kernel_launch(void* const* d_in, const int* in_sizes, int n_in,
                              void* d_out, int out_size, void* d_ws, size_t ws_size,
                              hipStream_t stream) {
    const float* prev_pcl  = (const float*)d_in[0];
    const int*   prev_mask = (const int*)  d_in[1];
    const int*   prev_grid = (const int*)  d_in[2];
    const float* cur_pcl   = (const float*)d_in[3];
    const int*   cur_mask  = (const int*)  d_in[4];
    const int*   cur_grid  = (const int*)  d_in[5];
    const float* W     = (const float*)d_in[6];
    const float* bvec  = (const float*)d_in[7];
    const float* gam   = (const float*)d_in[8];
    const float* bet   = (const float*)d_in[9];
    const float* mean  = (const float*)d_in[10];
    const float* var   = (const float*)d_in[11];
    float* out = (float*)d_out;

    float*  consts = (float*)d_ws;
    int*    head   = (int*)((char*)d_ws + WS_HEAD_OFF);
    float4* node   = (float4*)((char*)d_ws + WS_HEAD_OFF
                               + (size_t)NCLOUD * P_CELLS * sizeof(int));

    hipMemsetAsync(head, 0xFF, (size_t)NCLOUD * P_CELLS * sizeof(int), stream);

    build_lists<<<(NCLOUD * N_PTS + 255) / 256, 256, 0, stream>>>(
        prev_pcl, prev_mask, prev_grid, cur_pcl, cur_mask, cur_grid,
        W, bvec, gam, bet, mean, var, consts,
        head, node);

    dim3 ggrid(P_CELLS / 256, NCLOUD);
    gather_kernel<<<ggrid, 256, 0, stream>>>(head, node, consts, out);
}

// Round 2
// 449.941 us; speedup vs baseline: 1.0209x; 1.0019x over previous
//
#include <hip/hip_runtime.h>

// Problem constants
#define N_PTS   100000
#define P_CELLS 409600          // 640*640
#define NCLOUD  4               // B=2 batches x {prev, cur}; cloud c = b*2 + t

// Workspace layout (~13 MB used):
//   [0)      k0[64],k1[64],k2[64],k3[64]  fused constants (1 KB)
//   [1024)   head[4*P] ints               (6.55 MB)
//   [+...]   node[4*N] float4             (6.4 MB)  {x,y,z,next-as-bits}
#define WS_HEAD_OFF 1024

typedef float v2f __attribute__((ext_vector_type(2)));
typedef float v4f __attribute__((ext_vector_type(4)));

// ---------------------------------------------------------------------------
// Kernel 1: build per-cell linked lists of masked points with fat nodes.
//   head[c*P + p] -> most recent gid, node[gid].w -> prev gid bits, -1 ends.
// 2D grid: blockIdx.y = cloud c (no integer div / pointer selects per thread;
// each block streams exactly one cloud's arrays).
// Block (0,0) additionally fuses the Linear+BN constants (consts are only
// read by gather, a later dispatch -> no race).
// ---------------------------------------------------------------------------
__global__ void build_lists(
    const float* __restrict__ prev_pcl, const int* __restrict__ prev_mask,
    const int*   __restrict__ prev_grid,
    const float* __restrict__ cur_pcl,  const int* __restrict__ cur_mask,
    const int*   __restrict__ cur_grid,
    const float* __restrict__ W,     const float* __restrict__ bvec,
    const float* __restrict__ gamma, const float* __restrict__ beta,
    const float* __restrict__ mean,  const float* __restrict__ var,
    float* __restrict__ k,
    int* __restrict__ head, float4* __restrict__ node)
{
    if (blockIdx.x == 0 && blockIdx.y == 0 && threadIdx.x < 64) {
        const int d = threadIdx.x;
        const float s = gamma[d] * rsqrtf(var[d] + 1e-5f);
        k[d]       = W[d * 3 + 0] * s;
        k[64 + d]  = W[d * 3 + 1] * s;
        k[128 + d] = W[d * 3 + 2] * s;
        k[192 + d] = (bvec[d] - mean[d]) * s + beta[d];
    }

    const int n = blockIdx.x * blockDim.x + threadIdx.x;
    if (n >= N_PTS) return;
    const int c = blockIdx.y;               // cloud 0..3, wave-uniform
    const int t = c & 1;
    const int b = c >> 1;
    const int*   msk = t ? cur_mask : prev_mask;   // uniform selects -> SALU
    const int*   grd = t ? cur_grid : prev_grid;
    const float* pcl = t ? cur_pcl  : prev_pcl;
    const int e = b * N_PTS + n;
    if (!msk[e]) return;
    const int p = grd[e];
    const float* q = pcl + (size_t)e * 3;
    const int gid = c * N_PTS + n;
    int old = atomicExch(&head[c * P_CELLS + p], gid);
    node[gid] = make_float4(q[0], q[1], q[2], __int_as_float(old));
}

// ---------------------------------------------------------------------------
// Kernel 2: gather. One thread per (cloud c, cell p): chase chain (one 16 B
// load per hop), accumulate acc in VGPRs. Inner loop is PACKED FP32
// (ext_vector_type(2) -> v_pk_fma_f32 / v_pk_max_f32): 32 iterations of
// {3 pk_fma + pk_max + pk_fma} instead of 64 scalar.
// All acc indices are compile-time constants (full unroll) — runtime
// indexing demoted acc to scratch in a prior session and cost +160 us.
// Epilogue: LDS transpose per 16-feature group; wave stores are 16 B/lane
// NONTEMPORAL (output is write-once streaming, 419 MB >> L2 — nt keeps L2
// free for the node chain lines). head is read-once -> nt load too.
// Group 0 needs no leading barrier (no prior LDS reads to protect).
// ---------------------------------------------------------------------------
#define LDS_STRIDE 260   // 260 words = 1040 B = 65*16 -> rows stay 16B-aligned
__global__ __launch_bounds__(256) void gather_kernel(
    const int* __restrict__ head, const float4* __restrict__ node,
    const float* __restrict__ k,   // k0|k1|k2|k3, 64 each
    float* __restrict__ out)
{
    __shared__ float lds[16 * LDS_STRIDE];

    const int tid  = threadIdx.x;
    const int lane = tid & 63;
    const int wv   = tid >> 6;                          // wave id 0..3
    const int c    = blockIdx.y;                        // cloud 0..3
    const int cell0 = blockIdx.x * 256;                 // block's first cell
    const int p    = cell0 + tid;

    int idx = __builtin_nontemporal_load(&head[c * P_CELLS + p]);  // coalesced

    v2f acc[32];
#pragma unroll
    for (int i = 0; i < 32; ++i) acc[i] = (v2f){0.f, 0.f};

    const v2f* __restrict__ k0 = (const v2f*)(k);        // wave-uniform -> s_load
    const v2f* __restrict__ k1 = (const v2f*)(k + 64);
    const v2f* __restrict__ k2 = (const v2f*)(k + 128);
    const v2f* __restrict__ k3 = (const v2f*)(k + 192);

    while (__ballot(idx >= 0)) {
        const bool act = (idx >= 0);
        float4 nd = node[act ? idx : 0];                // predicated fat node
        const float m = act ? 1.f : 0.f;
        if (act) idx = __float_as_int(nd.w);
        v2f xv = nd.x, yv = nd.y, zv = nd.z, mv = m;    // scalar splats
        const v2f zero = (v2f){0.f, 0.f};
#pragma unroll
        for (int i = 0; i < 32; ++i) {
            v2f v = __builtin_elementwise_fma(xv, k0[i],
                    __builtin_elementwise_fma(yv, k1[i],
                    __builtin_elementwise_fma(zv, k2[i], k3[i])));
            v2f r = __builtin_elementwise_max(v, zero); // max kills NaN from poison node[0]
            acc[i] = __builtin_elementwise_fma(r, mv, acc[i]);
        }
    }

    // Epilogue: 4 groups of 16 features through LDS. FULL unroll: all acc[]
    // indices static -> acc stays in VGPRs.
    float* obase = out + (size_t)c * 64u * P_CELLS + cell0;
#pragma unroll
    for (int g = 0; g < 4; ++g) {
        if (g) __syncthreads();                         // reads(g-1) done
#pragma unroll
        for (int f = 0; f < 16; ++f) {
            const int feat = g * 16 + f;                // static
            lds[f * LDS_STRIDE + tid] = acc[feat >> 1][feat & 1];
        }
        __syncthreads();
#pragma unroll
        for (int r = 0; r < 4; ++r) {
            const int f = r * 4 + wv;                   // wave-uniform feature
            v4f v = *(const v4f*)&lds[f * LDS_STRIDE + lane * 4];
            __builtin_nontemporal_store(
                v, (v4f*)(obase + (size_t)(g * 16 + f) * P_CELLS + lane * 4));
        }
    }
}

// ---------------------------------------------------------------------------
extern "C" void kernel_launch(void* const* d_in, const int* in_sizes, int n_in,
                              void* d_out, int out_size, void* d_ws, size_t ws_size,
                              hipStream_t stream) {
    const float* prev_pcl  = (const float*)d_in[0];
    const int*   prev_mask = (const int*)  d_in[1];
    const int*   prev_grid = (const int*)  d_in[2];
    const float* cur_pcl   = (const float*)d_in[3];
    const int*   cur_mask  = (const int*)  d_in[4];
    const int*   cur_grid  = (const int*)  d_in[5];
    const float* W     = (const float*)d_in[6];
    const float* bvec  = (const float*)d_in[7];
    const float* gam   = (const float*)d_in[8];
    const float* bet   = (const float*)d_in[9];
    const float* mean  = (const float*)d_in[10];
    const float* var   = (const float*)d_in[11];
    float* out = (float*)d_out;

    float*  consts = (float*)d_ws;
    int*    head   = (int*)((char*)d_ws + WS_HEAD_OFF);
    float4* node   = (float4*)((char*)d_ws + WS_HEAD_OFF
                               + (size_t)NCLOUD * P_CELLS * sizeof(int));

    hipMemsetAsync(head, 0xFF, (size_t)NCLOUD * P_CELLS * sizeof(int), stream);

    dim3 bgrid((N_PTS + 255) / 256, NCLOUD);
    build_lists<<<bgrid, 256, 0, stream>>>(
        prev_pcl, prev_mask, prev_grid, cur_pcl, cur_mask, cur_grid,
        W, bvec, gam, bet, mean, var, consts,
        head, node);

    dim3 ggrid(P_CELLS / 256, NCLOUD);
    gather_kernel<<<ggrid, 256, 0, stream>>>(head, node, consts, out);
}